// Round 5
// baseline (142.302 us; speedup 1.0000x reference)
//
#include <hip/hip_runtime.h>
#include <hip/hip_bf16.h>
#include <math.h>

// ChamferLoss: pred [32,4096,3] f32, gt [32,4096,3] f32 -> scalar f32.
//
// min_m d2 = p2 + min_m (g2[m] - 2*dot); packed v_pk_fma_f32 (2 queries per
// register pair) with VOP3P op_sel broadcasting target components straight
// from the ds_read_b128 quad; 2 targets/iter so mins fold as v_min3_f32.
// -> 2 VALU insts per (query,target) pair. Useful floor = 27.3 us.
//
// R4 post-mortem: launch_bounds(256,2) only sets MIN waves/EU; allocator
// still squeezed to 48 VGPRs and shuffled mn[]/targets through AGPRs
// (v_accvgpr_* are VALU insts) -> VALUBusy 66%, 91 us. R5:
//  - amdgpu_waves_per_eu(2,2): pins occupancy target to exactly 2 waves/EU
//    (= our 2 blocks/CU), VGPR budget 256, no AGPR shuffle (~85 needed).
//  - replace 1MB 0xFF memset + 2.1M global atomicMin with plain stores of
//    per-tsplit partial mins (8 MB ws) merged in the finish kernel
//    (fallback to atomicMin path if ws_size < 8 MB).

#define TPB   256
#define QPT   16            // queries per thread; 4096 per block (all of them)
#define QP    (QPT / 2)     // packed query pairs
#define NPTS  4096
#define TSPL  8
#define TCH   (NPTS / TSPL) // 512 targets per block (8 KB LDS)
#define NQTOT (2 * 32 * NPTS)          // 262144 query slots
#define WS_PLAIN ((size_t)TSPL * NQTOT * 4)  // 8 MB partial-min layout

typedef float vf2 __attribute__((ext_vector_type(2)));
typedef float vf4 __attribute__((ext_vector_type(4)));

// d = q * bcast(g.lo) + bcast(g.hi)   [one v_pk_fma_f32]
__device__ __forceinline__ vf2 pk_fma_blo_bhi(vf2 q, vf2 g) {
    vf2 d;
    asm("v_pk_fma_f32 %0, %1, %2, %3 op_sel:[0,0,1] op_sel_hi:[1,0,1]"
        : "=v"(d) : "v"(q), "v"(g), "v"(g));
    return d;
}
// d = q * bcast(g.hi) + c
__device__ __forceinline__ vf2 pk_fma_bhi(vf2 q, vf2 g, vf2 c) {
    vf2 d;
    asm("v_pk_fma_f32 %0, %1, %2, %3 op_sel:[0,1,0] op_sel_hi:[1,1,1]"
        : "=v"(d) : "v"(q), "v"(g), "v"(c));
    return d;
}
// d = q * bcast(g.lo) + c
__device__ __forceinline__ vf2 pk_fma_blo(vf2 q, vf2 g, vf2 c) {
    vf2 d;
    asm("v_pk_fma_f32 %0, %1, %2, %3 op_sel:[0,0,0] op_sel_hi:[1,0,1]"
        : "=v"(d) : "v"(q), "v"(g), "v"(c));
    return d;
}

// Shared body: compute per-query partial mins over this block's target slice.
// Returns via mn[] (min of g2-2dot) and q regs for p2.
template <bool PLAIN>
__global__ __attribute__((amdgpu_flat_work_group_size(256, 256)))
__attribute__((amdgpu_waves_per_eu(2, 2)))
void chamfer_main(const float* __restrict__ pred,
                  const float* __restrict__ gt,
                  void* __restrict__ wsout)
{
    // grid.x = 512: dir (2) x batch (32) x tsplit (8)
    const int bx  = blockIdx.x;
    const int dir = bx >> 8;
    const int rem = bx & 255;
    const int b   = rem >> 3;
    const int kt  = rem & 7;

    const float* __restrict__ qbase = (dir ? gt : pred) + (size_t)b * NPTS * 3;
    const float* __restrict__ tbase = (dir ? pred : gt) + (size_t)b * NPTS * 3;

    __shared__ vf4 sT[TCH];     // (-2x, -2y, -2z, x^2+y^2+z^2)  8 KB

    const int tid = threadIdx.x;

    // Stage this block's 512-target slice: 2 points per thread
    for (int j = tid; j < TCH; j += TPB) {
        const float* tp = tbase + (size_t)(kt * TCH + j) * 3;
        float x = tp[0], y = tp[1], z = tp[2];
        vf4 t; t[0] = -2.0f * x; t[1] = -2.0f * y; t[2] = -2.0f * z;
        t[3] = fmaf(x, x, fmaf(y, y, z * z));
        sT[j] = t;
    }

    // Load 16 queries per thread, packed 2-per-register-pair
    vf2 qx2[QP], qy2[QP], qz2[QP];
    float mn[QPT];
#pragma unroll
    for (int p = 0; p < QP; ++p) {
#pragma unroll
        for (int h = 0; h < 2; ++h) {
            const int i = 2 * p + h;
            const float* q = qbase + (size_t)(i * TPB + tid) * 3;
            qx2[p][h] = q[0]; qy2[p][h] = q[1]; qz2[p][h] = q[2];
            mn[i] = 1e30f;
        }
    }

    __syncthreads();

    // 2 targets x 8 query-pairs per iter: 48 pk_fma + 16 min3 = 64 VALU
    // insts per 2 ds_read_b128  -> VALU-bound, 2 insts per (q,t) pair.
#pragma unroll 2
    for (int j = 0; j < TCH; j += 2) {
        const vf4 G0 = sT[j];
        const vf4 G1 = sT[j + 1];
        const vf2 g0xy = __builtin_shufflevector(G0, G0, 0, 1);
        const vf2 g0zw = __builtin_shufflevector(G0, G0, 2, 3);
        const vf2 g1xy = __builtin_shufflevector(G1, G1, 0, 1);
        const vf2 g1zw = __builtin_shufflevector(G1, G1, 2, 3);
#pragma unroll
        for (int p = 0; p < QP; ++p) {
            vf2 d0 = pk_fma_blo_bhi(qz2[p], g0zw);   // qz*g.z + g.w
            d0 = pk_fma_bhi(qy2[p], g0xy, d0);       // + qy*g.y
            d0 = pk_fma_blo(qx2[p], g0xy, d0);       // + qx*g.x
            vf2 d1 = pk_fma_blo_bhi(qz2[p], g1zw);
            d1 = pk_fma_bhi(qy2[p], g1xy, d1);
            d1 = pk_fma_blo(qx2[p], g1xy, d1);
            mn[2 * p]     = fminf(fminf(d0[0], d1[0]), mn[2 * p]);     // v_min3
            mn[2 * p + 1] = fminf(fminf(d0[1], d1[1]), mn[2 * p + 1]); // v_min3
        }
    }

    // d2 = p2 + min, clamp >= 1e-12.
    const int dirb = dir * 32 + b;
#pragma unroll
    for (int p = 0; p < QP; ++p) {
        vf2 p2 = qx2[p] * qx2[p] + qy2[p] * qy2[p] + qz2[p] * qz2[p];
#pragma unroll
        for (int h = 0; h < 2; ++h) {
            const int i = 2 * p + h;
            float d2 = fmaxf(mn[i] + p2[h], 1e-12f);
            if (PLAIN) {
                // per-tsplit partial slab, plain coalesced store
                float* wq = (float*)wsout + ((size_t)kt * NQTOT)
                          + (size_t)dirb * NPTS;
                wq[i * TPB + tid] = d2;
            } else {
                unsigned int* wq = (unsigned int*)wsout + (size_t)dirb * NPTS;
                atomicMin(&wq[i * TPB + tid], __float_as_uint(d2));
            }
        }
    }
}

// PLAIN path: min over 8 tsplit slabs, sqrt, mean, accumulate into out[0]
__global__ __launch_bounds__(TPB) void chamfer_finish_plain(
    const float* __restrict__ wspart,
    float* __restrict__ out)
{
    __shared__ float swave[TPB / 64];
    const int tid = threadIdx.x;

    float s = 0.0f;
#pragma unroll
    for (int r = 0; r < 4; ++r) {
        const int slot = blockIdx.x * (TPB * 4) + r * TPB + tid;
        float m = wspart[slot];
#pragma unroll
        for (int k = 1; k < TSPL; ++k)
            m = fminf(m, wspart[(size_t)k * NQTOT + slot]);
        s += sqrtf(m);
    }

#pragma unroll
    for (int off = 32; off > 0; off >>= 1)
        s += __shfl_down(s, off, 64);
    const int wid = tid >> 6, lane = tid & 63;
    if (lane == 0) swave[wid] = s;
    __syncthreads();
    if (tid == 0) {
        float tot = swave[0] + swave[1] + swave[2] + swave[3];
        atomicAdd(out, tot * (1.0f / 131072.0f));
    }
}

// ATOMIC path: sqrt + mean over merged mins
__global__ __launch_bounds__(TPB) void chamfer_finish_atomic(
    const unsigned int* __restrict__ wsmin,
    float* __restrict__ out)
{
    __shared__ float swave[TPB / 64];
    const int tid  = threadIdx.x;
    const int base = blockIdx.x * (TPB * 4) + tid;

    float s = 0.0f;
#pragma unroll
    for (int r = 0; r < 4; ++r)
        s += sqrtf(__uint_as_float(wsmin[base + r * TPB]));

#pragma unroll
    for (int off = 32; off > 0; off >>= 1)
        s += __shfl_down(s, off, 64);
    const int wid = tid >> 6, lane = tid & 63;
    if (lane == 0) swave[wid] = s;
    __syncthreads();
    if (tid == 0) {
        float tot = swave[0] + swave[1] + swave[2] + swave[3];
        atomicAdd(out, tot * (1.0f / 131072.0f));
    }
}

extern "C" void kernel_launch(void* const* d_in, const int* in_sizes, int n_in,
                              void* d_out, int out_size, void* d_ws, size_t ws_size,
                              hipStream_t stream)
{
    const float* pred = (const float*)d_in[0];
    const float* gt   = (const float*)d_in[1];
    float* out        = (float*)d_out;

    hipMemsetAsync(d_out, 0, sizeof(float), stream);

    if (ws_size >= WS_PLAIN) {
        // no init needed: every slab slot is written by exactly one block
        chamfer_main<true><<<dim3(512), dim3(TPB), 0, stream>>>(pred, gt, d_ws);
        chamfer_finish_plain<<<dim3(NQTOT / (TPB * 4)), dim3(TPB), 0, stream>>>(
            (const float*)d_ws, out);
    } else {
        hipMemsetAsync(d_ws, 0xFF, (size_t)NQTOT * sizeof(unsigned int), stream);
        chamfer_main<false><<<dim3(512), dim3(TPB), 0, stream>>>(pred, gt, d_ws);
        chamfer_finish_atomic<<<dim3(NQTOT / (TPB * 4)), dim3(TPB), 0, stream>>>(
            (const unsigned int*)d_ws, out);
    }
}